// Round 3
// baseline (372.064 us; speedup 1.0000x reference)
//
#include <hip/hip_runtime.h>

#define N_NODES 20000
#define N_EDGES 320000
#define IN_F    168
#define HID     256

// ---------------- graph prep ----------------

__global__ void edge_count_deg(const int* __restrict__ ei, const float* __restrict__ ew,
                               float* __restrict__ deg, int* __restrict__ counts) {
    int e = blockIdx.x * blockDim.x + threadIdx.x;
    if (e >= N_EDGES) return;
    int d = ei[N_EDGES + e];            // dst row of edge_index
    atomicAdd(&deg[d], ew[e]);
    atomicAdd(&counts[d], 1);
}

__global__ void finalize_dinv(float* __restrict__ deg) {
    int i = blockIdx.x * blockDim.x + threadIdx.x;
    if (i >= N_NODES) return;
    float d = deg[i] + 1.0f;            // self-loop weight 1.0
    deg[i] = rsqrtf(d);                 // deg >= 1 always
}

// single-block exclusive scan over counts -> offs (n+1), wave-shuffle based
__global__ void scan_counts(const int* __restrict__ counts, int* __restrict__ offs, int n) {
    int tid  = threadIdx.x;
    int lane = tid & 63;
    int wv   = tid >> 6;                // 16 waves
    __shared__ int wsum[16];
    __shared__ int s_total;
    __shared__ int s_carry;
    if (tid == 0) s_carry = 0;
    __syncthreads();
    for (int base = 0; base < n; base += 1024) {
        int i = base + tid;
        int v = (i < n) ? counts[i] : 0;
        int incl = v;
        #pragma unroll
        for (int d = 1; d < 64; d <<= 1) {
            int t = __shfl_up(incl, d);
            if (lane >= d) incl += t;
        }
        if (lane == 63) wsum[wv] = incl;
        __syncthreads();
        if (wv == 0) {
            int w = (lane < 16) ? wsum[lane] : 0;
            int winc = w;
            #pragma unroll
            for (int d = 1; d < 16; d <<= 1) {
                int t = __shfl_up(winc, d);
                if (lane >= d) winc += t;
            }
            if (lane < 16) wsum[lane] = winc - w;   // exclusive wave offsets
            if (lane == 15) s_total = winc;         // chunk total
        }
        __syncthreads();
        int c = s_carry;
        if (i < n) offs[i] = c + wsum[wv] + incl - v;
        __syncthreads();
        if (tid == 0) s_carry = c + s_total;
        __syncthreads();
    }
    if (tid == 0) offs[n] = s_carry;
}

__global__ void scatter_edges(const int* __restrict__ ei, const float* __restrict__ ew,
                              const float* __restrict__ dinv, const int* __restrict__ offs,
                              int* __restrict__ cursor, int* __restrict__ csr_src,
                              float* __restrict__ csr_norm) {
    int e = blockIdx.x * blockDim.x + threadIdx.x;
    if (e >= N_EDGES) return;
    int s = ei[e];
    int d = ei[N_EDGES + e];
    int pos = offs[d] + atomicAdd(&cursor[d], 1);
    csr_src[pos]  = s;
    csr_norm[pos] = dinv[s] * ew[e] * dinv[d];
}

// ---------------- SGEMM: C[M,256] = A[M,K] * W[256,K]^T ----------------
// 64x64 tile, 256 threads, 4x4 microtile, BK=16, double-buffered LDS (1 barrier/iter)

#define BM 64
#define BN 64
#define BK 16
#define LDP 68   // padded LDS row stride: 272B, 16B-aligned, conflict-free

__global__ __launch_bounds__(256) void sgemm_nt(const float* __restrict__ A,
                                                const float* __restrict__ W,
                                                float* __restrict__ C,
                                                int M, int K) {
    __shared__ __align__(16) float As[2][BK][LDP];
    __shared__ __align__(16) float Ws[2][BK][LDP];
    const int tid = threadIdx.x;
    const int bm = blockIdx.x * BM;
    const int bn = blockIdx.y * BN;
    const int tx = tid & 15;            // 0..15 -> 4 cols each
    const int ty = tid >> 4;            // 0..15 -> 4 rows each
    const int r  = tid >> 2;            // 0..63  staging row
    const int c4 = (tid & 3) * 4;       // 0,4,8,12 staging k-offset
    const int gm = bm + r;
    const int gn = bn + r;              // always < 256
    float acc[4][4] = {};

    const int niter = (K + BK - 1) / BK;
    const float4 z4 = make_float4(0.f, 0.f, 0.f, 0.f);

    // preload tile 0
    float4 a0 = (gm < M && c4 + 4 <= K) ? *(const float4*)&A[(size_t)gm * K + c4] : z4;
    float4 w0 = (c4 + 4 <= K) ? *(const float4*)&W[(size_t)gn * K + c4] : z4;
    As[0][c4 + 0][r] = a0.x; As[0][c4 + 1][r] = a0.y;
    As[0][c4 + 2][r] = a0.z; As[0][c4 + 3][r] = a0.w;
    Ws[0][c4 + 0][r] = w0.x; Ws[0][c4 + 1][r] = w0.y;
    Ws[0][c4 + 2][r] = w0.z; Ws[0][c4 + 3][r] = w0.w;
    __syncthreads();

    for (int it = 0; it < niter; ++it) {
        const int cur = it & 1;
        const bool nxt = (it + 1) < niter;
        float4 an, wn;
        if (nxt) {
            int k = (it + 1) * BK + c4;
            an = (gm < M && k + 4 <= K) ? *(const float4*)&A[(size_t)gm * K + k] : z4;
            wn = (k + 4 <= K) ? *(const float4*)&W[(size_t)gn * K + k] : z4;
        }
        #pragma unroll
        for (int k = 0; k < BK; ++k) {
            float4 a = *(const float4*)&As[cur][k][ty * 4];
            float4 b = *(const float4*)&Ws[cur][k][tx * 4];
            acc[0][0] += a.x * b.x; acc[0][1] += a.x * b.y;
            acc[0][2] += a.x * b.z; acc[0][3] += a.x * b.w;
            acc[1][0] += a.y * b.x; acc[1][1] += a.y * b.y;
            acc[1][2] += a.y * b.z; acc[1][3] += a.y * b.w;
            acc[2][0] += a.z * b.x; acc[2][1] += a.z * b.y;
            acc[2][2] += a.z * b.z; acc[2][3] += a.z * b.w;
            acc[3][0] += a.w * b.x; acc[3][1] += a.w * b.y;
            acc[3][2] += a.w * b.z; acc[3][3] += a.w * b.w;
        }
        if (nxt) {
            const int nb = cur ^ 1;
            As[nb][c4 + 0][r] = an.x; As[nb][c4 + 1][r] = an.y;
            As[nb][c4 + 2][r] = an.z; As[nb][c4 + 3][r] = an.w;
            Ws[nb][c4 + 0][r] = wn.x; Ws[nb][c4 + 1][r] = wn.y;
            Ws[nb][c4 + 2][r] = wn.z; Ws[nb][c4 + 3][r] = wn.w;
        }
        __syncthreads();
    }

    #pragma unroll
    for (int i = 0; i < 4; ++i) {
        int row = bm + ty * 4 + i;
        if (row < M) {
            float4 v = make_float4(acc[i][0], acc[i][1], acc[i][2], acc[i][3]);
            *(float4*)&C[(size_t)row * HID + bn + tx * 4] = v;
        }
    }
}

// ---------------- aggregation (+self-loop, +bias, ReLU) ----------------
// one WAVE per dst node; 64 lanes x float4 = one 1KB row per load issue; 4 rows in flight

__global__ __launch_bounds__(256) void aggregate4(const float4* __restrict__ xw4,
                                                  const float* __restrict__ dinv,
                                                  const int* __restrict__ offs,
                                                  const int* __restrict__ csr_src,
                                                  const float* __restrict__ csr_norm,
                                                  const float4* __restrict__ bias4,
                                                  float4* __restrict__ out4) {
    int wave = threadIdx.x >> 6;
    int lane = threadIdx.x & 63;
    int n = blockIdx.x * 4 + wave;      // N_NODES % 4 == 0
    float di = dinv[n];
    float sw = di * di;
    float4 v = xw4[(size_t)n * 64 + lane];
    float ax = sw * v.x, ay = sw * v.y, az = sw * v.z, aw = sw * v.w;

    int p0 = offs[n], p1 = offs[n + 1];
    int p = p0;
    for (; p + 4 <= p1; p += 4) {
        int   s0 = csr_src[p],     s1 = csr_src[p + 1];
        int   s2 = csr_src[p + 2], s3 = csr_src[p + 3];
        float w0 = csr_norm[p],     w1 = csr_norm[p + 1];
        float w2 = csr_norm[p + 2], w3 = csr_norm[p + 3];
        float4 r0 = xw4[(size_t)s0 * 64 + lane];
        float4 r1 = xw4[(size_t)s1 * 64 + lane];
        float4 r2 = xw4[(size_t)s2 * 64 + lane];
        float4 r3 = xw4[(size_t)s3 * 64 + lane];
        ax += w0 * r0.x + w1 * r1.x + w2 * r2.x + w3 * r3.x;
        ay += w0 * r0.y + w1 * r1.y + w2 * r2.y + w3 * r3.y;
        az += w0 * r0.z + w1 * r1.z + w2 * r2.z + w3 * r3.z;
        aw += w0 * r0.w + w1 * r1.w + w2 * r2.w + w3 * r3.w;
    }
    for (; p < p1; ++p) {
        int   s0 = csr_src[p];
        float w0 = csr_norm[p];
        float4 r0 = xw4[(size_t)s0 * 64 + lane];
        ax += w0 * r0.x; ay += w0 * r0.y; az += w0 * r0.z; aw += w0 * r0.w;
    }

    float4 b = bias4[lane];
    ax += b.x; ay += b.y; az += b.z; aw += b.w;
    float4 o;
    o.x = ax > 0.f ? ax : 0.f;
    o.y = ay > 0.f ? ay : 0.f;
    o.z = az > 0.f ? az : 0.f;
    o.w = aw > 0.f ? aw : 0.f;
    out4[(size_t)n * 64 + lane] = o;
}

// ---------------- launch ----------------

extern "C" void kernel_launch(void* const* d_in, const int* in_sizes, int n_in,
                              void* d_out, int out_size, void* d_ws, size_t ws_size,
                              hipStream_t stream) {
    const float* x  = (const float*)d_in[0];
    const int*   ei = (const int*)d_in[1];
    const float* ew = (const float*)d_in[2];
    const float* W1 = (const float*)d_in[3];
    const float* b1 = (const float*)d_in[4];
    const float* W2 = (const float*)d_in[5];
    const float* b2 = (const float*)d_in[6];
    float* out = (float*)d_out;

    char* ws = (char*)d_ws;
    float* deg      = (float*)(ws);                         // 20000 f32  (becomes dinv)
    int*   counts   = (int*)(ws + 80000);                   // 20000 i32
    int*   cursor   = (int*)(ws + 160000);                  // 20000 i32
    int*   offs     = (int*)(ws + 240000);                  // 20001 i32 (pad to 80016)
    int*   csr_src  = (int*)(ws + 320016);                  // 320000 i32
    float* csr_norm = (float*)(ws + 1600016);               // 320000 f32
    float* xw       = (float*)(ws + 2880016);               // 20000x256 f32
    float* h1       = (float*)(ws + 23360016);              // 20000x256 f32

    hipMemsetAsync(d_ws, 0, 240000, stream);

    const int TB = 256;
    edge_count_deg<<<(N_EDGES + TB - 1) / TB, TB, 0, stream>>>(ei, ew, deg, counts);
    finalize_dinv<<<(N_NODES + TB - 1) / TB, TB, 0, stream>>>(deg);
    scan_counts<<<1, 1024, 0, stream>>>(counts, offs, N_NODES);
    scatter_edges<<<(N_EDGES + TB - 1) / TB, TB, 0, stream>>>(ei, ew, deg, offs, cursor,
                                                              csr_src, csr_norm);

    dim3 g1((N_NODES + BM - 1) / BM, HID / BN);
    // layer 1
    sgemm_nt<<<g1, 256, 0, stream>>>(x, W1, xw, N_NODES, IN_F);
    aggregate4<<<N_NODES / 4, 256, 0, stream>>>((const float4*)xw, deg, offs, csr_src,
                                                csr_norm, (const float4*)b1, (float4*)h1);
    // layer 2
    sgemm_nt<<<g1, 256, 0, stream>>>(h1, W2, xw, N_NODES, HID);
    aggregate4<<<N_NODES / 4, 256, 0, stream>>>((const float4*)xw, deg, offs, csr_src,
                                                csr_norm, (const float4*)b2, (float4*)out);
}

// Round 4
// 338.489 us; speedup vs baseline: 1.0992x; 1.0992x over previous
//
#include <hip/hip_runtime.h>

#define N_NODES 20000
#define N_EDGES 320000
#define IN_F    168
#define HID     256

// ---------------- graph prep ----------------

__global__ void edge_count_deg(const int* __restrict__ ei, const float* __restrict__ ew,
                               float* __restrict__ deg, int* __restrict__ counts) {
    int e = blockIdx.x * blockDim.x + threadIdx.x;
    if (e >= N_EDGES) return;
    int d = ei[N_EDGES + e];            // dst row of edge_index
    atomicAdd(&deg[d], ew[e]);
    atomicAdd(&counts[d], 1);
}

__global__ void finalize_dinv(float* __restrict__ deg) {
    int i = blockIdx.x * blockDim.x + threadIdx.x;
    if (i >= N_NODES) return;
    float d = deg[i] + 1.0f;            // self-loop weight 1.0
    deg[i] = rsqrtf(d);                 // deg >= 1 always
}

// single-block exclusive scan over counts -> offs (n+1), wave-shuffle based
__global__ void scan_counts(const int* __restrict__ counts, int* __restrict__ offs, int n) {
    int tid  = threadIdx.x;
    int lane = tid & 63;
    int wv   = tid >> 6;                // 16 waves
    __shared__ int wsum[16];
    __shared__ int s_total;
    __shared__ int s_carry;
    if (tid == 0) s_carry = 0;
    __syncthreads();
    for (int base = 0; base < n; base += 1024) {
        int i = base + tid;
        int v = (i < n) ? counts[i] : 0;
        int incl = v;
        #pragma unroll
        for (int d = 1; d < 64; d <<= 1) {
            int t = __shfl_up(incl, d);
            if (lane >= d) incl += t;
        }
        if (lane == 63) wsum[wv] = incl;
        __syncthreads();
        if (wv == 0) {
            int w = (lane < 16) ? wsum[lane] : 0;
            int winc = w;
            #pragma unroll
            for (int d = 1; d < 16; d <<= 1) {
                int t = __shfl_up(winc, d);
                if (lane >= d) winc += t;
            }
            if (lane < 16) wsum[lane] = winc - w;   // exclusive wave offsets
            if (lane == 15) s_total = winc;         // chunk total
        }
        __syncthreads();
        int c = s_carry;
        if (i < n) offs[i] = c + wsum[wv] + incl - v;
        __syncthreads();
        if (tid == 0) s_carry = c + s_total;
        __syncthreads();
    }
    if (tid == 0) offs[n] = s_carry;
}

__global__ void scatter_edges(const int* __restrict__ ei, const float* __restrict__ ew,
                              const float* __restrict__ dinv, const int* __restrict__ offs,
                              int* __restrict__ cursor, int* __restrict__ csr_src,
                              float* __restrict__ csr_norm) {
    int e = blockIdx.x * blockDim.x + threadIdx.x;
    if (e >= N_EDGES) return;
    int s = ei[e];
    int d = ei[N_EDGES + e];
    int pos = offs[d] + atomicAdd(&cursor[d], 1);
    csr_src[pos]  = s;
    csr_norm[pos] = dinv[s] * ew[e] * dinv[d];
}

// ---------------- SGEMM: C[M,256] = A[M,K] * W[256,K]^T ----------------
// 64x64 tile, 256 threads, 4x4 microtile, BK=8, single LDS buffer + register
// prefetch of the next tile (loads issued right after the barrier, before compute).
// LDS row stride 72: staging write banks = (8*(c2+j)+r)%32 -> 2 lanes/bank (free).

#define BM 64
#define BN 64
#define BK 8
#define LDA 72

__global__ __launch_bounds__(256, 4) void sgemm_nt(const float* __restrict__ A,
                                                   const float* __restrict__ W,
                                                   float* __restrict__ C,
                                                   int M, int K) {
    __shared__ __align__(16) float As[BK][LDA];
    __shared__ __align__(16) float Ws[BK][LDA];
    const int tid = threadIdx.x;
    const int bm = blockIdx.x * BM;
    const int bn = blockIdx.y * BN;
    const int tx = tid & 15;            // 0..15 -> 4 cols each
    const int ty = tid >> 4;            // 0..15 -> 4 rows each
    const int r  = tid >> 2;            // 0..63  staging row
    const int c2 = (tid & 3) * 2;       // 0,2,4,6 staging k-offset
    const int gm = bm + r;
    const int gn = bn + r;              // always < 256
    float acc[4][4] = {};

    const int niter = K / BK;           // K % 8 == 0 for both layers
    const float2 z2 = make_float2(0.f, 0.f);

    // prefetch tile 0 into registers
    float2 pa = (gm < M) ? *(const float2*)&A[(size_t)gm * K + c2] : z2;
    float2 pw = *(const float2*)&W[(size_t)gn * K + c2];

    for (int it = 0; it < niter; ++it) {
        As[c2 + 0][r] = pa.x; As[c2 + 1][r] = pa.y;
        Ws[c2 + 0][r] = pw.x; Ws[c2 + 1][r] = pw.y;
        __syncthreads();
        if (it + 1 < niter) {           // uniform branch
            int k = (it + 1) * BK + c2;
            pa = (gm < M) ? *(const float2*)&A[(size_t)gm * K + k] : z2;
            pw = *(const float2*)&W[(size_t)gn * K + k];
        }
        #pragma unroll
        for (int k = 0; k < BK; ++k) {
            float4 a = *(const float4*)&As[k][ty * 4];
            float4 b = *(const float4*)&Ws[k][tx * 4];
            acc[0][0] += a.x * b.x; acc[0][1] += a.x * b.y;
            acc[0][2] += a.x * b.z; acc[0][3] += a.x * b.w;
            acc[1][0] += a.y * b.x; acc[1][1] += a.y * b.y;
            acc[1][2] += a.y * b.z; acc[1][3] += a.y * b.w;
            acc[2][0] += a.z * b.x; acc[2][1] += a.z * b.y;
            acc[2][2] += a.z * b.z; acc[2][3] += a.z * b.w;
            acc[3][0] += a.w * b.x; acc[3][1] += a.w * b.y;
            acc[3][2] += a.w * b.z; acc[3][3] += a.w * b.w;
        }
        __syncthreads();
    }

    #pragma unroll
    for (int i = 0; i < 4; ++i) {
        int row = bm + ty * 4 + i;
        if (row < M) {
            float4 v = make_float4(acc[i][0], acc[i][1], acc[i][2], acc[i][3]);
            *(float4*)&C[(size_t)row * HID + bn + tx * 4] = v;
        }
    }
}

// ---------------- aggregation (+self-loop, +bias, ReLU) ----------------
// one WAVE per dst node; 64 lanes x float4 = one 1KB row per load issue; 4 rows in flight

__global__ __launch_bounds__(256) void aggregate4(const float4* __restrict__ xw4,
                                                  const float* __restrict__ dinv,
                                                  const int* __restrict__ offs,
                                                  const int* __restrict__ csr_src,
                                                  const float* __restrict__ csr_norm,
                                                  const float4* __restrict__ bias4,
                                                  float4* __restrict__ out4) {
    int wave = threadIdx.x >> 6;
    int lane = threadIdx.x & 63;
    int n = blockIdx.x * 4 + wave;      // N_NODES % 4 == 0
    float di = dinv[n];
    float sw = di * di;
    float4 v = xw4[(size_t)n * 64 + lane];
    float ax = sw * v.x, ay = sw * v.y, az = sw * v.z, aw = sw * v.w;

    int p0 = offs[n], p1 = offs[n + 1];
    int p = p0;
    for (; p + 4 <= p1; p += 4) {
        int   s0 = csr_src[p],     s1 = csr_src[p + 1];
        int   s2 = csr_src[p + 2], s3 = csr_src[p + 3];
        float w0 = csr_norm[p],     w1 = csr_norm[p + 1];
        float w2 = csr_norm[p + 2], w3 = csr_norm[p + 3];
        float4 r0 = xw4[(size_t)s0 * 64 + lane];
        float4 r1 = xw4[(size_t)s1 * 64 + lane];
        float4 r2 = xw4[(size_t)s2 * 64 + lane];
        float4 r3 = xw4[(size_t)s3 * 64 + lane];
        ax += w0 * r0.x + w1 * r1.x + w2 * r2.x + w3 * r3.x;
        ay += w0 * r0.y + w1 * r1.y + w2 * r2.y + w3 * r3.y;
        az += w0 * r0.z + w1 * r1.z + w2 * r2.z + w3 * r3.z;
        aw += w0 * r0.w + w1 * r1.w + w2 * r2.w + w3 * r3.w;
    }
    for (; p < p1; ++p) {
        int   s0 = csr_src[p];
        float w0 = csr_norm[p];
        float4 r0 = xw4[(size_t)s0 * 64 + lane];
        ax += w0 * r0.x; ay += w0 * r0.y; az += w0 * r0.z; aw += w0 * r0.w;
    }

    float4 b = bias4[lane];
    ax += b.x; ay += b.y; az += b.z; aw += b.w;
    float4 o;
    o.x = ax > 0.f ? ax : 0.f;
    o.y = ay > 0.f ? ay : 0.f;
    o.z = az > 0.f ? az : 0.f;
    o.w = aw > 0.f ? aw : 0.f;
    out4[(size_t)n * 64 + lane] = o;
}

// ---------------- launch ----------------

extern "C" void kernel_launch(void* const* d_in, const int* in_sizes, int n_in,
                              void* d_out, int out_size, void* d_ws, size_t ws_size,
                              hipStream_t stream) {
    const float* x  = (const float*)d_in[0];
    const int*   ei = (const int*)d_in[1];
    const float* ew = (const float*)d_in[2];
    const float* W1 = (const float*)d_in[3];
    const float* b1 = (const float*)d_in[4];
    const float* W2 = (const float*)d_in[5];
    const float* b2 = (const float*)d_in[6];
    float* out = (float*)d_out;

    char* ws = (char*)d_ws;
    float* deg      = (float*)(ws);                         // 20000 f32  (becomes dinv)
    int*   counts   = (int*)(ws + 80000);                   // 20000 i32
    int*   cursor   = (int*)(ws + 160000);                  // 20000 i32
    int*   offs     = (int*)(ws + 240000);                  // 20001 i32 (pad to 80016)
    int*   csr_src  = (int*)(ws + 320016);                  // 320000 i32
    float* csr_norm = (float*)(ws + 1600016);               // 320000 f32
    float* xw       = (float*)(ws + 2880016);               // 20000x256 f32
    float* h1       = (float*)(ws + 23360016);              // 20000x256 f32

    hipMemsetAsync(d_ws, 0, 240000, stream);

    const int TB = 256;
    edge_count_deg<<<(N_EDGES + TB - 1) / TB, TB, 0, stream>>>(ei, ew, deg, counts);
    finalize_dinv<<<(N_NODES + TB - 1) / TB, TB, 0, stream>>>(deg);
    scan_counts<<<1, 1024, 0, stream>>>(counts, offs, N_NODES);
    scatter_edges<<<(N_EDGES + TB - 1) / TB, TB, 0, stream>>>(ei, ew, deg, offs, cursor,
                                                              csr_src, csr_norm);

    dim3 g1((N_NODES + BM - 1) / BM, HID / BN);
    // layer 1
    sgemm_nt<<<g1, 256, 0, stream>>>(x, W1, xw, N_NODES, IN_F);
    aggregate4<<<N_NODES / 4, 256, 0, stream>>>((const float4*)xw, deg, offs, csr_src,
                                                csr_norm, (const float4*)b1, (float4*)h1);
    // layer 2
    sgemm_nt<<<g1, 256, 0, stream>>>(h1, W2, xw, N_NODES, HID);
    aggregate4<<<N_NODES / 4, 256, 0, stream>>>((const float4*)xw, deg, offs, csr_src,
                                                csr_norm, (const float4*)b2, (float4*)out);
}